// Round 3
// baseline (61.465 us; speedup 1.0000x reference)
//
#include <hip/hip_runtime.h>

#define NC 1024
#define NS 32
#define DD 512
#define MARGIN 0.3f

// Reduce v[8] (per-sample column partials) across the 64 lanes of a wave.
// Halving butterfly: step with mask m splits the j-index space by lane bit
// log2(m) -- 7 shuffles instead of 48. After masks 1,2,4 each lane holds one
// j = bitrev3(lane&7) summed over its 8-lane group; masks 8,16,32 finish the
// 64-lane sum. Returns that value (same j for lanes l, l^8, l^16, l^32).
__device__ __forceinline__ float reduce_cols8(float v[8], int lane) {
#pragma unroll
    for (int m = 1, len = 8; m <= 4; m <<= 1, len >>= 1) {
        const int half = len >> 1;
#pragma unroll
        for (int i = 0; i < half; ++i) {
            float lo = v[i], hi = v[i + half];
            float send = (lane & m) ? lo : hi;
            float recv = __shfl_xor(send, m);
            v[i] = (lane & m) ? (hi + recv) : (lo + recv);
        }
    }
    float r = v[0];
    r += __shfl_xor(r, 8);
    r += __shfl_xor(r, 16);
    r += __shfl_xor(r, 32);
    return r;
}

// One block per class, 512 threads. g = t>>7 (0..3) picks sample stride-4
// subset, col4 = t&127 the thread's float4 column. Whole 128 KB class tile is
// register-resident (16x global_load_dwordx4 per thread, each HBM byte read
// exactly once, fully coalesced). Final mean over classes is done by the last
// block to finish (counter in d_ws, zeroed by a memset node each call).
__global__ __launch_bounds__(512) void ccl_fused(const float* __restrict__ emb,
                                                 float* __restrict__ cls,
                                                 unsigned* __restrict__ cnt,
                                                 float* __restrict__ out) {
    const int c = blockIdx.x;
    const int t = threadIdx.x;
    const int g = t >> 7;
    const int col4 = t & 127;
    const int lane = t & 63;
    const int wv = t >> 6;
    const float4* posv = (const float4*)(emb + (size_t)c * (2 * NS * DD));
    const float4* negv = posv + NS * DD / 4;

    __shared__ float4 s_part[4][128];
    __shared__ float s_wap[8][8];
    __shared__ float s_wnd[8][8];
    __shared__ float s_fin[8];
    __shared__ unsigned s_old;

    // ---- load: 8 pos rows then 8 neg rows (rows s = 4j+g) ----
    float4 p[8], n[8];
#pragma unroll
    for (int j = 0; j < 8; ++j) p[j] = posv[(4 * j + g) * (DD / 4) + col4];
#pragma unroll
    for (int j = 0; j < 8; ++j) n[j] = negv[(4 * j + g) * (DD / 4) + col4];

    // ---- anchor: per-thread column sum over 8 rows, LDS combine of 4 groups ----
    float4 acc = p[0];
#pragma unroll
    for (int j = 1; j < 8; ++j) {
        acc.x += p[j].x; acc.y += p[j].y; acc.z += p[j].z; acc.w += p[j].w;
    }
    s_part[g][col4] = acc;
    __syncthreads();
    float4 a;
    {
        float4 x0 = s_part[0][col4], x1 = s_part[1][col4];
        float4 x2 = s_part[2][col4], x3 = s_part[3][col4];
        a.x = (x0.x + x1.x + x2.x + x3.x) * (1.f / NS);
        a.y = (x0.y + x1.y + x2.y + x3.y) * (1.f / NS);
        a.z = (x0.z + x1.z + x2.z + x3.z) * (1.f / NS);
        a.w = (x0.w + x1.w + x2.w + x3.w) * (1.f / NS);
    }

    // ---- per-(sample, column) squared-diff partials ----
    float apc[8], ndc[8];
#pragma unroll
    for (int j = 0; j < 8; ++j) {
        float dx = p[j].x - a.x, dy = p[j].y - a.y, dz = p[j].z - a.z, dw = p[j].w - a.w;
        apc[j] = dx * dx + dy * dy + dz * dz + dw * dw;
        dx = n[j].x - a.x; dy = n[j].y - a.y; dz = n[j].z - a.z; dw = n[j].w - a.w;
        ndc[j] = dx * dx + dy * dy + dz * dz + dw * dw;
    }

    // ---- reduce across 64 columns (one wave) ----
    float rap = reduce_cols8(apc, lane);
    float rnd = reduce_cols8(ndc, lane);
    if (lane < 8) {
        const int jm = ((lane & 1) << 2) | (lane & 2) | ((lane & 4) >> 2);
        s_wap[wv][jm] = rap;
        s_wnd[wv][jm] = rnd;
    }
    __syncthreads();

    // ---- per-class min + hinge (one wave), then last-block global mean ----
    if (t < NS) {
        const int sg = t & 3, sj = t >> 2;  // sample s = 4*sj + sg
        float ap = s_wap[2 * sg][sj] + s_wap[2 * sg + 1][sj];
        float nd = s_wnd[2 * sg][sj] + s_wnd[2 * sg + 1][sj];
        float an = nd;
#pragma unroll
        for (int m = 1; m < 32; m <<= 1) an = fminf(an, __shfl_xor(an, m));
        float l = fmaxf(ap - an + MARGIN, 0.f);
#pragma unroll
        for (int m = 1; m < 32; m <<= 1) l += __shfl_xor(l, m);
        if (t == 0) {
            __hip_atomic_store(&cls[c], l, __ATOMIC_RELAXED, __HIP_MEMORY_SCOPE_AGENT);
            s_old = __hip_atomic_fetch_add(cnt, 1u, __ATOMIC_ACQ_REL, __HIP_MEMORY_SCOPE_AGENT);
        }
    }
    __syncthreads();

    if (s_old == NC - 1) {
        // Last block: deterministic fixed-order mean of the 1024 class losses.
        float v = __hip_atomic_load(&cls[t], __ATOMIC_ACQUIRE, __HIP_MEMORY_SCOPE_AGENT) +
                  __hip_atomic_load(&cls[t + 512], __ATOMIC_ACQUIRE, __HIP_MEMORY_SCOPE_AGENT);
#pragma unroll
        for (int m = 1; m < 64; m <<= 1) v += __shfl_xor(v, m);
        if (lane == 0) s_fin[wv] = v;
        __syncthreads();
        if (t == 0) {
            float tot = 0.f;
#pragma unroll
            for (int w = 0; w < 8; ++w) tot += s_fin[w];
            out[0] = tot * (1.f / NC);
        }
    }
}

extern "C" void kernel_launch(void* const* d_in, const int* in_sizes, int n_in,
                              void* d_out, int out_size, void* d_ws, size_t ws_size,
                              hipStream_t stream) {
    const float* emb = (const float*)d_in[0];       // (2*NC*NS, DD) f32
    unsigned* cnt = (unsigned*)d_ws;                // completion counter
    float* cls = (float*)((char*)d_ws + 256);       // NC per-class losses
    float* out = (float*)d_out;                     // 1 float
    hipMemsetAsync(cnt, 0, 4, stream);              // zero counter each call
    ccl_fused<<<NC, 512, 0, stream>>>(emb, cls, cnt, out);
}